// Round 7
// baseline (513.520 us; speedup 1.0000x reference)
//
#include <hip/hip_runtime.h>
#include <hip/hip_bf16.h>
#include <hip/hip_fp16.h>

#define GN 100000
#define GE 600000
#define SCAN_NBLK 98   // ceil(GN / 1024)
#define ALD 132        // fp32 LDS leading dim: 128 + 4

typedef __bf16    bf16x8 __attribute__((ext_vector_type(8)));
typedef __bf16    bf16x4 __attribute__((ext_vector_type(4)));
typedef _Float16  f16x8  __attribute__((ext_vector_type(8)));
typedef float     f32x4  __attribute__((ext_vector_type(4)));

// ---------------------------------------------------------------------------
// Weight pre-conversion: fp32 -> (hi, lo) bf16 planes, ONCE per launch.
// ---------------------------------------------------------------------------
__global__ __launch_bounds__(256) void convert_w(
    const float* __restrict__ Win, const float* __restrict__ Wc,
    const float* __restrict__ Wout,
    __bf16* __restrict__ hi, __bf16* __restrict__ lo)
{
    const int i = blockIdx.x * 256 + threadIdx.x;
    if (i >= 98304) return;
    float v;
    if (i < 16384)      v = Win[i];
    else if (i < 65536) v = Wc[i - 16384];
    else                v = Wout[i - 65536];
    const __bf16 h = (__bf16)v;
    hi[i] = h;
    lo[i] = (__bf16)(v - (float)h);
}

// ---------------------------------------------------------------------------
// Standalone streaming gather (round-6, unchanged): Agg[row] = sum of
// neighbor fp16 rows. One row per wave, zero LDS, max TLP. ~44us = LLC
// random-read floor (154MB touched at ~3.5TB/s).
// ---------------------------------------------------------------------------
__global__ __launch_bounds__(256, 8) void gather_rows(
    const uint* __restrict__ Hw,
    const int* __restrict__ row_start,
    const int* __restrict__ deg,
    const int* __restrict__ csr,
    float* __restrict__ Agg)
{
    const int wave = threadIdx.x >> 6;
    const int lane = threadIdx.x & 63;
    const int row  = blockIdx.x * 4 + wave;
    if (row >= GN) return;

    const int start = row_start[row];
    const int dg    = deg[row];
    float2 acc = make_float2(0.f, 0.f);

    for (int b = 0; b < dg; b += 64) {
        const int n = min(dg - b, 64);
        const int idx = csr[start + min(b + lane, dg - 1)];
        for (int k = 0; k < n; k += 8) {
            uint t[8];
#pragma unroll
            for (int u = 0; u < 8; ++u) {
                const int s = __shfl(idx, min(k + u, n - 1));
                t[u] = Hw[(size_t)s * 64 + lane];
            }
            const int m = min(n - k, 8);
#pragma unroll
            for (int u = 0; u < 8; ++u) {
                if (u < m) {
                    union { uint uu; _Float16 h[2]; } cv;
                    cv.uu = t[u];
                    acc.x += (float)cv.h[0];
                    acc.y += (float)cv.h[1];
                }
            }
        }
    }
    *(float2*)&Agg[(size_t)row * 128 + lane * 2] = acc;
}

// ---------------------------------------------------------------------------
// GEMM sub-phase: C_tile = Acc_buf @ W^T into acc[2][2], with 1-deep weight
// prefetch (round-5 body, factored).
// ---------------------------------------------------------------------------
__device__ __forceinline__ void gemm_tile(
    const float* __restrict__ AccBuf,
    const __bf16* __restrict__ Whi, const __bf16* __restrict__ Wlo,
    const int wn, const int quad, const int l15,
    f32x4 acc[2][2])
{
#pragma unroll
    for (int i = 0; i < 2; ++i)
#pragma unroll
        for (int j = 0; j < 2; ++j) acc[i][j] = (f32x4)(0.0f);

    bf16x8 whA[2], wlA[2], whB[2], wlB[2];
#pragma unroll
    for (int nt = 0; nt < 2; ++nt) {
        const int n = wn + nt * 16 + l15;
        whA[nt] = *(const bf16x8*)(Whi + (size_t)n * 128 + quad * 8);
        wlA[nt] = *(const bf16x8*)(Wlo + (size_t)n * 128 + quad * 8);
    }
#pragma unroll
    for (int ks = 0; ks < 4; ++ks) {
        const int kt = ks * 32 + quad * 8;
        if (ks < 3) {
            const int kn = kt + 32;
#pragma unroll
            for (int nt = 0; nt < 2; ++nt) {
                const int n = wn + nt * 16 + l15;
                whB[nt] = *(const bf16x8*)(Whi + (size_t)n * 128 + kn);
                wlB[nt] = *(const bf16x8*)(Wlo + (size_t)n * 128 + kn);
            }
        }
        bf16x8 ahi[2], alo[2];
#pragma unroll
        for (int mt = 0; mt < 2; ++mt) {
            const float* ap = &AccBuf[(mt * 16 + l15) * ALD + kt];
            const f32x4 p = *(const f32x4*)ap;
            const f32x4 q = *(const f32x4*)(ap + 4);
#pragma unroll
            for (int e = 0; e < 4; ++e) {
                const __bf16 hp = (__bf16)p[e];
                const __bf16 hq = (__bf16)q[e];
                ahi[mt][e]     = hp;
                ahi[mt][e + 4] = hq;
                alo[mt][e]     = (__bf16)(p[e] - (float)hp);
                alo[mt][e + 4] = (__bf16)(q[e] - (float)hq);
            }
        }
#pragma unroll
        for (int mt = 0; mt < 2; ++mt)
#pragma unroll
            for (int nt = 0; nt < 2; ++nt) {
                acc[mt][nt] = __builtin_amdgcn_mfma_f32_16x16x32_bf16(
                    ahi[mt], whA[nt], acc[mt][nt], 0, 0, 0);
                acc[mt][nt] = __builtin_amdgcn_mfma_f32_16x16x32_bf16(
                    ahi[mt], wlA[nt], acc[mt][nt], 0, 0, 0);
                acc[mt][nt] = __builtin_amdgcn_mfma_f32_16x16x32_bf16(
                    alo[mt], whA[nt], acc[mt][nt], 0, 0, 0);
            }
        if (ks < 3) {
#pragma unroll
            for (int nt = 0; nt < 2; ++nt) {
                whA[nt] = whB[nt];
                wlA[nt] = wlB[nt];
            }
        }
    }
}

// ---------------------------------------------------------------------------
// Dense GIN layer, TWO-TILE pipelined: 64 rows/block (two 32-row tiles),
// double-buffered LDS. Both tiles' global loads issued up-front (tile1's
// HBM latency hides under tile0's LDS-write + GEMM); C0-stage overlaps B1.
//   issue(s0,a0,s1,a1) -> A0:LDS0 -> bar -> B0 -> A1:LDS1 -> bar ->
//   C0stage(LDS0) -> B1 -> bar -> C0store | C1stage(LDS1) -> bar -> C1store
// ---------------------------------------------------------------------------
template<bool HASAGG>
__global__ __launch_bounds__(256, 3) void gin_layer(
    const float* __restrict__ H, int ldH,
    const float* __restrict__ Agg,             // [GN,128] fp32
    const __bf16* __restrict__ Whi,            // [128,128]
    const __bf16* __restrict__ Wlo,
    const float* __restrict__ bias,            // [128]
    float* __restrict__ C, int ldC,
    _Float16* __restrict__ HfOut)              // dense fp16 copy of C
{
    __shared__ float Acc[2][32 * ALD];   // 33792 B

    const int tid  = threadIdx.x;
    const int wave = tid >> 6;
    const int lane = tid & 63;
    const int row0 = blockIdx.x * 64;
    const int wn   = wave * 32;
    const int quad = lane >> 4;
    const int l15  = lane & 15;
    const int c    = (lane & 31) * 4;
    const int hp2  = lane >> 5;          // 0/1

    // ---- issue ALL global loads for both tiles (16-32 loads in flight) ----
    f32x4 s0[4], a0[4], s1[4], a1[4];
#pragma unroll
    for (int p = 0; p < 4; ++p) {
        const int r0 = min(row0 + wave * 8 + p * 2 + hp2, GN - 1);
        s0[p] = *(const f32x4*)(H + (size_t)r0 * ldH + c);
        if (HASAGG) a0[p] = *(const f32x4*)(Agg + (size_t)r0 * 128 + c);
    }
#pragma unroll
    for (int p = 0; p < 4; ++p) {
        const int r1 = min(row0 + 32 + wave * 8 + p * 2 + hp2, GN - 1);
        s1[p] = *(const f32x4*)(H + (size_t)r1 * ldH + c);
        if (HASAGG) a1[p] = *(const f32x4*)(Agg + (size_t)r1 * 128 + c);
    }

    // ---- A0: combine + write LDS0 (waits only the first 8-16 loads) ----
#pragma unroll
    for (int p = 0; p < 4; ++p) {
        const int r = wave * 8 + p * 2 + hp2;
        f32x4 v = s0[p];
        if (HASAGG) v += a0[p];
        *(f32x4*)&Acc[0][r * ALD + c] = v;
    }
    __syncthreads();

    // ---- B0: GEMM tile0 ----
    f32x4 acc0[2][2];
    gemm_tile(Acc[0], Whi, Wlo, wn, quad, l15, acc0);

    // ---- A1: combine + write LDS1 (s1/a1 long arrived) ----
#pragma unroll
    for (int p = 0; p < 4; ++p) {
        const int r = wave * 8 + p * 2 + hp2;
        f32x4 v = s1[p];
        if (HASAGG) v += a1[p];
        *(f32x4*)&Acc[1][r * ALD + c] = v;
    }
    __syncthreads();   // B0 done reading LDS0; LDS1 visible

    // ---- C0-stage into LDS0, then B1 (overlap) ----
#pragma unroll
    for (int nt = 0; nt < 2; ++nt) {
        const int col = wn + nt * 16 + l15;
        const float b = bias[col];
#pragma unroll
        for (int mt = 0; mt < 2; ++mt)
#pragma unroll
            for (int r4 = 0; r4 < 4; ++r4)
                Acc[0][(mt * 16 + quad * 4 + r4) * ALD + col] = acc0[mt][nt][r4] + b;
    }

    f32x4 acc1[2][2];
    gemm_tile(Acc[1], Whi, Wlo, wn, quad, l15, acc1);
    __syncthreads();   // C0-stage written; B1 done reading LDS1

    // ---- C0-store (fire-and-forget) ----
#pragma unroll
    for (int p = 0; p < 4; ++p) {
        const int q  = tid + p * 256;
        const int r  = q >> 5;
        const int c4 = (q & 31) * 4;
        const int gr = row0 + r;
        if (gr < GN)
            *(float4*)(C + (size_t)gr * ldC + c4) = *(const float4*)&Acc[0][r * ALD + c4];
    }
#pragma unroll
    for (int p = 0; p < 2; ++p) {
        const int q = tid + p * 256;
        const int r = q >> 4;
        const int g = (q & 15) * 8;
        const int gr = row0 + r;
        if (gr < GN) {
            const float4 a = *(const float4*)&Acc[0][r * ALD + g];
            const float4 b = *(const float4*)&Acc[0][r * ALD + g + 4];
            f16x8 o = {(_Float16)a.x, (_Float16)a.y, (_Float16)a.z, (_Float16)a.w,
                       (_Float16)b.x, (_Float16)b.y, (_Float16)b.z, (_Float16)b.w};
            *(f16x8*)&HfOut[(size_t)gr * 128 + g] = o;
        }
    }

    // ---- C1-stage into LDS1 ----
#pragma unroll
    for (int nt = 0; nt < 2; ++nt) {
        const int col = wn + nt * 16 + l15;
        const float b = bias[col];
#pragma unroll
        for (int mt = 0; mt < 2; ++mt)
#pragma unroll
            for (int r4 = 0; r4 < 4; ++r4)
                Acc[1][(mt * 16 + quad * 4 + r4) * ALD + col] = acc1[mt][nt][r4] + b;
    }
    __syncthreads();

    // ---- C1-store ----
#pragma unroll
    for (int p = 0; p < 4; ++p) {
        const int q  = tid + p * 256;
        const int r  = q >> 5;
        const int c4 = (q & 31) * 4;
        const int gr = row0 + 32 + r;
        if (gr < GN)
            *(float4*)(C + (size_t)gr * ldC + c4) = *(const float4*)&Acc[1][r * ALD + c4];
    }
#pragma unroll
    for (int p = 0; p < 2; ++p) {
        const int q = tid + p * 256;
        const int r = q >> 4;
        const int g = (q & 15) * 8;
        const int gr = row0 + 32 + r;
        if (gr < GN) {
            const float4 a = *(const float4*)&Acc[1][r * ALD + g];
            const float4 b = *(const float4*)&Acc[1][r * ALD + g + 4];
            f16x8 o = {(_Float16)a.x, (_Float16)a.y, (_Float16)a.z, (_Float16)a.w,
                       (_Float16)b.x, (_Float16)b.y, (_Float16)b.z, (_Float16)b.w};
            *(f16x8*)&HfOut[(size_t)gr * 128 + g] = o;
        }
    }
}

// ---------------------------------------------------------------------------
// Fused layer 3 + output projection + softmax (round-6, unchanged).
// ---------------------------------------------------------------------------
__global__ __launch_bounds__(256, 3) void gin_final(
    const float* __restrict__ cat3,            // [GN,384]
    const float* __restrict__ Agg,             // [GN,128]
    const __bf16* __restrict__ Whi3,
    const __bf16* __restrict__ Wlo3,
    const float* __restrict__ b3,
    const __bf16* __restrict__ WhiO,           // [64,512]
    const __bf16* __restrict__ WloO,
    const float* __restrict__ bO,
    float* __restrict__ out)                   // [GN,64]
{
    constexpr int CLD = 68;

    __shared__ float Smem[32 * ALD];
    float* const Acc = Smem;
    float* const Cst = Smem;

    const int tid  = threadIdx.x;
    const int wave = tid >> 6;
    const int lane = tid & 63;
    const int row0 = blockIdx.x * 32;
    const int quad = lane >> 4;
    const int l15  = lane & 15;

    // ---- Phase A (wave-local): Acc = cat3 block 2 + Agg ----
    {
        const int c = (lane & 31) * 4;
        f32x4 sv[4];
#pragma unroll
        for (int p = 0; p < 4; ++p) {
            const int r = wave * 8 + p * 2 + (lane >> 5);
            sv[p] = *(const f32x4*)(cat3 + (size_t)(row0 + r) * 384 + 256 + c);
            sv[p] += *(const f32x4*)(Agg + (size_t)(row0 + r) * 128 + c);
        }
#pragma unroll
        for (int p = 0; p < 4; ++p) {
            const int r = wave * 8 + p * 2 + (lane >> 5);
            *(f32x4*)&Acc[r * ALD + c] = sv[p];
        }
    }
    __syncthreads();

    // ---- Phase B1: GEMM1 (K=128) -> h3 ----
    const int wn = wave * 32;
    f32x4 acc1[2][2];
    gemm_tile(Acc, Whi3, Wlo3, wn, quad, l15, acc1);
    __syncthreads();

    // h3 + b3 -> Acc
#pragma unroll
    for (int nt = 0; nt < 2; ++nt) {
        const int col = wn + nt * 16 + l15;
        const float b = b3[col];
#pragma unroll
        for (int mt = 0; mt < 2; ++mt)
#pragma unroll
            for (int r4 = 0; r4 < 4; ++r4)
                Acc[(mt * 16 + quad * 4 + r4) * ALD + col] = acc1[mt][nt][r4] + b;
    }
    __syncthreads();

    // ---- Phase B2: GEMM2 (K=512), 1m x 2n x 2k waves, 2-deep pipeline ----
    const int wk  = wave & 1;
    const int wn2 = (wave >> 1) * 32;
    f32x4 acc2[2][2];
#pragma unroll
    for (int i = 0; i < 2; ++i)
#pragma unroll
        for (int j = 0; j < 2; ++j) acc2[i][j] = (f32x4)(0.0f);

    f32x4 pA[2], qA[2], pB[2], qB[2];
    bf16x8 whA[2], wlA[2], whB[2], wlB[2];

    {
        const int kg = wk * 256 + quad * 8;
#pragma unroll
        for (int mt = 0; mt < 2; ++mt) {
            const int row = mt * 16 + l15;
            const float* ap = cat3 + (size_t)(row0 + row) * 384 + kg;
            pA[mt] = *(const f32x4*)ap;
            qA[mt] = *(const f32x4*)(ap + 4);
        }
#pragma unroll
        for (int nt = 0; nt < 2; ++nt) {
            const int n = wn2 + nt * 16 + l15;
            whA[nt] = *(const bf16x8*)(WhiO + (size_t)n * 512 + kg);
            wlA[nt] = *(const bf16x8*)(WloO + (size_t)n * 512 + kg);
        }
    }

#pragma unroll
    for (int ks = 0; ks < 8; ++ks) {
        if (ks < 7) {
            const int kg = wk * 256 + (ks + 1) * 32 + quad * 8;
#pragma unroll
            for (int mt = 0; mt < 2; ++mt) {
                const int row = mt * 16 + l15;
                if (kg < 384) {
                    const float* ap = cat3 + (size_t)(row0 + row) * 384 + kg;
                    pB[mt] = *(const f32x4*)ap;
                    qB[mt] = *(const f32x4*)(ap + 4);
                } else {
                    const float* ap = &Acc[row * ALD + (kg - 384)];
                    pB[mt] = *(const f32x4*)ap;
                    qB[mt] = *(const f32x4*)(ap + 4);
                }
            }
#pragma unroll
            for (int nt = 0; nt < 2; ++nt) {
                const int n = wn2 + nt * 16 + l15;
                whB[nt] = *(const bf16x8*)(WhiO + (size_t)n * 512 + kg);
                wlB[nt] = *(const bf16x8*)(WloO + (size_t)n * 512 + kg);
            }
        }
        bf16x8 ahi[2], alo[2];
#pragma unroll
        for (int mt = 0; mt < 2; ++mt) {
#pragma unroll
            for (int e = 0; e < 4; ++e) {
                const __bf16 hp = (__bf16)pA[mt][e];
                const __bf16 hq = (__bf16)qA[mt][e];
                ahi[mt][e]     = hp;
                ahi[mt][e + 4] = hq;
                alo[mt][e]     = (__bf16)(pA[mt][e] - (float)hp);
                alo[mt][e + 4] = (__bf16)(qA[mt][e] - (float)hq);
            }
        }
#pragma unroll
        for (int mt = 0; mt < 2; ++mt)
#pragma unroll
            for (int nt = 0; nt < 2; ++nt) {
                acc2[mt][nt] = __builtin_amdgcn_mfma_f32_16x16x32_bf16(
                    ahi[mt], whA[nt], acc2[mt][nt], 0, 0, 0);
                acc2[mt][nt] = __builtin_amdgcn_mfma_f32_16x16x32_bf16(
                    ahi[mt], wlA[nt], acc2[mt][nt], 0, 0, 0);
                acc2[mt][nt] = __builtin_amdgcn_mfma_f32_16x16x32_bf16(
                    alo[mt], whA[nt], acc2[mt][nt], 0, 0, 0);
            }
        if (ks < 7) {
#pragma unroll
            for (int mt = 0; mt < 2; ++mt) { pA[mt] = pB[mt]; qA[mt] = qB[mt]; }
#pragma unroll
            for (int nt = 0; nt < 2; ++nt) { whA[nt] = whB[nt]; wlA[nt] = wlB[nt]; }
        }
    }

    __syncthreads();   // all B2 reads of Acc done before Cst alias write

    if (wk == 1) {
#pragma unroll
        for (int nt = 0; nt < 2; ++nt)
#pragma unroll
            for (int mt = 0; mt < 2; ++mt)
#pragma unroll
                for (int r4 = 0; r4 < 4; ++r4)
                    Cst[(mt * 16 + quad * 4 + r4) * CLD + wn2 + nt * 16 + l15]
                        = acc2[mt][nt][r4];
    }
    __syncthreads();
    if (wk == 0) {
#pragma unroll
        for (int nt = 0; nt < 2; ++nt) {
            const int col = wn2 + nt * 16 + l15;
            const float b = bO[col];
#pragma unroll
            for (int mt = 0; mt < 2; ++mt)
#pragma unroll
                for (int r4 = 0; r4 < 4; ++r4) {
                    const int idx = (mt * 16 + quad * 4 + r4) * CLD + col;
                    Cst[idx] = Cst[idx] + acc2[mt][nt][r4] + b;
                }
        }
    }
    __syncthreads();

    for (int i = 0; i < 8; ++i) {
        const int r = wave * 8 + i;
        const float v = Cst[r * CLD + lane];
        float m = v;
#pragma unroll
        for (int off = 32; off > 0; off >>= 1) m = fmaxf(m, __shfl_xor(m, off));
        const float e = __expf(v - m);
        float s = e;
#pragma unroll
        for (int off = 32; off > 0; off >>= 1) s += __shfl_xor(s, off);
        out[(size_t)(row0 + r) * 64 + lane] = e / s;
    }
}

// ---------------------------------------------------------------------------
// CSR construction (unchanged)
// ---------------------------------------------------------------------------
__global__ __launch_bounds__(256) void count_deg(const int* __restrict__ dst,
                                                 int* __restrict__ deg)
{
    const int e = blockIdx.x * 256 + threadIdx.x;
    if (e < GE) atomicAdd(&deg[dst[e]], 1);
}

__global__ __launch_bounds__(256) void scan_pass1(const int* __restrict__ deg,
                                                  int* __restrict__ excl,
                                                  int* __restrict__ blockSums)
{
    __shared__ int s[256];
    const int t = threadIdx.x;
    const int base = blockIdx.x * 1024 + t * 4;

    int4 v = make_int4(0, 0, 0, 0);
    if (base + 3 < GN) {
        v = *(const int4*)(deg + base);
    } else {
        if (base + 0 < GN) v.x = deg[base + 0];
        if (base + 1 < GN) v.y = deg[base + 1];
        if (base + 2 < GN) v.z = deg[base + 2];
        if (base + 3 < GN) v.w = deg[base + 3];
    }
    const int mysum = v.x + v.y + v.z + v.w;
    s[t] = mysum;
    __syncthreads();
    for (int off = 1; off < 256; off <<= 1) {
        const int val = (t >= off) ? s[t - off] : 0;
        __syncthreads();
        s[t] += val;
        __syncthreads();
    }
    int4 o;
    o.x = s[t] - mysum;
    o.y = o.x + v.x;
    o.z = o.y + v.y;
    o.w = o.z + v.z;
    if (base + 3 < GN) {
        *(int4*)(excl + base) = o;
    } else {
        if (base + 0 < GN) excl[base + 0] = o.x;
        if (base + 1 < GN) excl[base + 1] = o.y;
        if (base + 2 < GN) excl[base + 2] = o.z;
        if (base + 3 < GN) excl[base + 3] = o.w;
    }
    if (t == 255) blockSums[blockIdx.x] = s[255];
}

__global__ __launch_bounds__(128) void scan_pass2(const int* __restrict__ blockSums,
                                                  int* __restrict__ blockOffs, int n)
{
    __shared__ int s[128];
    const int t = threadIdx.x;
    const int v = (t < n) ? blockSums[t] : 0;
    s[t] = v;
    __syncthreads();
    for (int off = 1; off < 128; off <<= 1) {
        const int val = (t >= off) ? s[t - off] : 0;
        __syncthreads();
        s[t] += val;
        __syncthreads();
    }
    if (t < n) blockOffs[t] = s[t] - v;
}

__global__ __launch_bounds__(256) void scan_pass3(int* __restrict__ excl,
                                                  const int* __restrict__ blockOffs,
                                                  int* __restrict__ cursor)
{
    const int i = blockIdx.x * 256 + threadIdx.x;
    if (i >= GN) return;
    const int v = excl[i] + blockOffs[i >> 10];
    excl[i]   = v;
    cursor[i] = v;
}

__global__ __launch_bounds__(256) void fill_csr(const int* __restrict__ src,
                                                const int* __restrict__ dst,
                                                int* __restrict__ cursor,
                                                int* __restrict__ csr)
{
    const int e = blockIdx.x * 256 + threadIdx.x;
    if (e >= GE) return;
    const int pos = atomicAdd(&cursor[dst[e]], 1);
    csr[pos] = src[e];
}

extern "C" void kernel_launch(void* const* d_in, const int* in_sizes, int n_in,
                              void* d_out, int out_size, void* d_ws, size_t ws_size,
                              hipStream_t stream)
{
    const float* x       = (const float*)d_in[0];
    const int*   src     = (const int*)d_in[1];
    const int*   dst     = ((const int*)d_in[1]) + GE;
    const float* W_in    = (const float*)d_in[2];
    const float* b_in    = (const float*)d_in[3];
    const float* W_convs = (const float*)d_in[4];
    const float* b_convs = (const float*)d_in[5];
    const float* W_out   = (const float*)d_in[6];
    const float* b_out   = (const float*)d_in[7];
    float*       out     = (float*)d_out;

    float*    cat3 = (float*)d_ws;
    _Float16* Hf   = (_Float16*)(cat3 + (size_t)GN * 384);
    float*    Agg  = (float*)(Hf + (size_t)GN * 128);
    int*      deg       = (int*)(Agg + (size_t)GN * 128);
    int*      row_start = deg + GN;
    int*      cursor    = row_start + GN;
    int*      blockSums = cursor + GN;
    int*      blockOffs = blockSums + 128;
    int*      csr       = blockOffs + 128;
    __bf16*   Whi       = (__bf16*)(csr + GE);
    __bf16*   Wlo       = Whi + 98304;

    const dim3 blk(256);
    const dim3 gblk(256);
    const int edge_blocks   = (GE + 255) / 256;
    const int node_blocks   = (GN + 255) / 256;
    const int layer_blocks  = (GN + 63) / 64;    // 1563 two-tile blocks
    const int final_blocks  = GN / 32;           // 3125 (exact)
    const int gather_blocks = (GN + 3) / 4;

    // --- CSR build ---
    hipMemsetAsync(deg, 0, GN * sizeof(int), stream);
    count_deg<<<edge_blocks, blk, 0, stream>>>(dst, deg);
    scan_pass1<<<SCAN_NBLK, blk, 0, stream>>>(deg, row_start, blockSums);
    scan_pass2<<<1, 128, 0, stream>>>(blockSums, blockOffs, SCAN_NBLK);
    scan_pass3<<<node_blocks, blk, 0, stream>>>(row_start, blockOffs, cursor);
    fill_csr<<<edge_blocks, blk, 0, stream>>>(src, dst, cursor, csr);

    // --- weight pre-conversion ---
    convert_w<<<(98304 + 255) / 256, blk, 0, stream>>>(W_in, W_convs, W_out, Whi, Wlo);

    // --- input projection -> cat3 block 0 + Hf (h0) ---
    gin_layer<false><<<layer_blocks, gblk, 0, stream>>>(
        x, 128, nullptr, Whi, Wlo, b_in, cat3, 384, Hf);

    // --- layer 1 ---
    gather_rows<<<gather_blocks, gblk, 0, stream>>>(
        (const uint*)Hf, row_start, deg, csr, Agg);
    gin_layer<true><<<layer_blocks, gblk, 0, stream>>>(
        cat3, 384, Agg, Whi + 16384, Wlo + 16384, b_convs, cat3 + 128, 384, Hf);

    // --- layer 2 ---
    gather_rows<<<gather_blocks, gblk, 0, stream>>>(
        (const uint*)Hf, row_start, deg, csr, Agg);
    gin_layer<true><<<layer_blocks, gblk, 0, stream>>>(
        cat3 + 128, 384, Agg, Whi + 32768, Wlo + 32768, b_convs + 128,
        cat3 + 256, 384, Hf);

    // --- layer 3 + output projection + softmax ---
    gather_rows<<<gather_blocks, gblk, 0, stream>>>(
        (const uint*)Hf, row_start, deg, csr, Agg);
    gin_final<<<final_blocks, gblk, 0, stream>>>(
        cat3, Agg, Whi + 49152, Wlo + 49152, b_convs + 256,
        Whi + 65536, Wlo + 65536, b_out, out);
}

// Round 9
// 459.467 us; speedup vs baseline: 1.1176x; 1.1176x over previous
//
#include <hip/hip_runtime.h>
#include <hip/hip_bf16.h>
#include <hip/hip_fp16.h>

#define GN 100000
#define GE 600000
#define SCAN_NBLK 98   // ceil(GN / 1024)
#define ALD 132        // fp32 LDS leading dim: 128 + 4

typedef __bf16    bf16x8 __attribute__((ext_vector_type(8)));
typedef _Float16  f16x8  __attribute__((ext_vector_type(8)));
typedef float     f32x4  __attribute__((ext_vector_type(4)));

// ---------------------------------------------------------------------------
// Weight pre-conversion: fp32 -> (hi, lo) bf16 planes, ONCE per launch.
// ---------------------------------------------------------------------------
__global__ __launch_bounds__(256) void convert_w(
    const float* __restrict__ Win, const float* __restrict__ Wc,
    const float* __restrict__ Wout,
    __bf16* __restrict__ hi, __bf16* __restrict__ lo)
{
    const int i = blockIdx.x * 256 + threadIdx.x;
    if (i >= 98304) return;
    float v;
    if (i < 16384)      v = Win[i];
    else if (i < 65536) v = Wc[i - 16384];
    else                v = Wout[i - 65536];
    const __bf16 h = (__bf16)v;
    hi[i] = h;
    lo[i] = (__bf16)(v - (float)h);
}

// ---------------------------------------------------------------------------
// Standalone streaming gather (round-6, unchanged): Agg[row] = sum of
// neighbor fp16 rows. One row per wave, zero LDS, max TLP.
// ---------------------------------------------------------------------------
__global__ __launch_bounds__(256, 8) void gather_rows(
    const uint* __restrict__ Hw,
    const int* __restrict__ row_start,
    const int* __restrict__ deg,
    const int* __restrict__ csr,
    float* __restrict__ Agg)
{
    const int wave = threadIdx.x >> 6;
    const int lane = threadIdx.x & 63;
    const int row  = blockIdx.x * 4 + wave;
    if (row >= GN) return;

    const int start = row_start[row];
    const int dg    = deg[row];
    float2 acc = make_float2(0.f, 0.f);

    for (int b = 0; b < dg; b += 64) {
        const int n = min(dg - b, 64);
        const int idx = csr[start + min(b + lane, dg - 1)];
        for (int k = 0; k < n; k += 8) {
            uint t[8];
#pragma unroll
            for (int u = 0; u < 8; ++u) {
                const int s = __shfl(idx, min(k + u, n - 1));
                t[u] = Hw[(size_t)s * 64 + lane];
            }
            const int m = min(n - k, 8);
#pragma unroll
            for (int u = 0; u < 8; ++u) {
                if (u < m) {
                    union { uint uu; _Float16 h[2]; } cv;
                    cv.uu = t[u];
                    acc.x += (float)cv.h[0];
                    acc.y += (float)cv.h[1];
                }
            }
        }
    }
    *(float2*)&Agg[(size_t)row * 128 + lane * 2] = acc;
}

// ---------------------------------------------------------------------------
// GEMM sub-phase: acc = AccBuf(32x128 fp32 LDS) @ W^T, 1-deep wgt prefetch.
// ---------------------------------------------------------------------------
__device__ __forceinline__ void gemm_tile(
    const float* __restrict__ AccBuf,
    const __bf16* __restrict__ Whi, const __bf16* __restrict__ Wlo,
    const int wn, const int quad, const int l15,
    f32x4 acc[2][2])
{
#pragma unroll
    for (int i = 0; i < 2; ++i)
#pragma unroll
        for (int j = 0; j < 2; ++j) acc[i][j] = (f32x4)(0.0f);

    bf16x8 whA[2], wlA[2], whB[2], wlB[2];
#pragma unroll
    for (int nt = 0; nt < 2; ++nt) {
        const int n = wn + nt * 16 + l15;
        whA[nt] = *(const bf16x8*)(Whi + (size_t)n * 128 + quad * 8);
        wlA[nt] = *(const bf16x8*)(Wlo + (size_t)n * 128 + quad * 8);
    }
#pragma unroll
    for (int ks = 0; ks < 4; ++ks) {
        const int kt = ks * 32 + quad * 8;
        if (ks < 3) {
            const int kn = kt + 32;
#pragma unroll
            for (int nt = 0; nt < 2; ++nt) {
                const int n = wn + nt * 16 + l15;
                whB[nt] = *(const bf16x8*)(Whi + (size_t)n * 128 + kn);
                wlB[nt] = *(const bf16x8*)(Wlo + (size_t)n * 128 + kn);
            }
        }
        bf16x8 ahi[2], alo[2];
#pragma unroll
        for (int mt = 0; mt < 2; ++mt) {
            const float* ap = &AccBuf[(mt * 16 + l15) * ALD + kt];
            const f32x4 p = *(const f32x4*)ap;
            const f32x4 q = *(const f32x4*)(ap + 4);
#pragma unroll
            for (int e = 0; e < 4; ++e) {
                const __bf16 hp = (__bf16)p[e];
                const __bf16 hq = (__bf16)q[e];
                ahi[mt][e]     = hp;
                ahi[mt][e + 4] = hq;
                alo[mt][e]     = (__bf16)(p[e] - (float)hp);
                alo[mt][e + 4] = (__bf16)(q[e] - (float)hq);
            }
        }
#pragma unroll
        for (int mt = 0; mt < 2; ++mt)
#pragma unroll
            for (int nt = 0; nt < 2; ++nt) {
                acc[mt][nt] = __builtin_amdgcn_mfma_f32_16x16x32_bf16(
                    ahi[mt], whA[nt], acc[mt][nt], 0, 0, 0);
                acc[mt][nt] = __builtin_amdgcn_mfma_f32_16x16x32_bf16(
                    ahi[mt], wlA[nt], acc[mt][nt], 0, 0, 0);
                acc[mt][nt] = __builtin_amdgcn_mfma_f32_16x16x32_bf16(
                    alo[mt], whA[nt], acc[mt][nt], 0, 0, 0);
            }
        if (ks < 3) {
#pragma unroll
            for (int nt = 0; nt < 2; ++nt) {
                whA[nt] = whB[nt];
                wlA[nt] = wlB[nt];
            }
        }
    }
}

// ---------------------------------------------------------------------------
// Dense GIN layer, 32-row tile / 256 threads. h_out = (h_in + Agg?) @ W^T + b
// with h stored as CONTIGUOUS fp16 [GN,128] (single copy; gather reads it
// too). Layer 0 reads fp32 x instead. One fp16 output stream.
// ---------------------------------------------------------------------------
template<bool HASAGG>
__global__ __launch_bounds__(256, 3) void gin_layer(
    const float* __restrict__ Hf32,       // layer-0 input x (fp32), !HASAGG
    const _Float16* __restrict__ H16,     // prev h (fp16), HASAGG
    const float* __restrict__ Agg,        // [GN,128] fp32
    const __bf16* __restrict__ Whi,       // [128,128]
    const __bf16* __restrict__ Wlo,
    const float* __restrict__ bias,       // [128]
    _Float16* __restrict__ Hout)          // [GN,128] fp16
{
    __shared__ float Acc[32 * ALD];      // 16896 B

    const int tid  = threadIdx.x;
    const int wave = tid >> 6;
    const int lane = tid & 63;
    const int row0 = blockIdx.x * 32;    // 3125*32 == GN exactly
    const int wn   = wave * 32;
    const int quad = lane >> 4;
    const int l15  = lane & 15;
    const int c8   = l15 * 8;

    // ---- Phase A (wave-local): stage own 8 rows, fp32 into LDS ----
#pragma unroll
    for (int p = 0; p < 2; ++p) {
        const int r = wave * 8 + p * 4 + quad;
        const size_t g = (size_t)(row0 + r) * 128 + c8;
        f32x4 v0, v1;
        if (HASAGG) {
            const f16x8 hv = *(const f16x8*)(H16 + g);
            const f32x4 a0 = *(const f32x4*)(Agg + g);
            const f32x4 a1 = *(const f32x4*)(Agg + g + 4);
#pragma unroll
            for (int e = 0; e < 4; ++e) {
                v0[e] = (float)hv[e]     + a0[e];
                v1[e] = (float)hv[e + 4] + a1[e];
            }
        } else {
            v0 = *(const f32x4*)(Hf32 + g);
            v1 = *(const f32x4*)(Hf32 + g + 4);
        }
        *(f32x4*)&Acc[r * ALD + c8]     = v0;
        *(f32x4*)&Acc[r * ALD + c8 + 4] = v1;
    }
    __syncthreads();

    // ---- Phase B: GEMM ----
    f32x4 acc[2][2];
    gemm_tile(Acc, Whi, Wlo, wn, quad, l15, acc);
    __syncthreads();

    // ---- Phase C: stage acc+bias to LDS, then ONE coalesced fp16 store ----
#pragma unroll
    for (int nt = 0; nt < 2; ++nt) {
        const int col = wn + nt * 16 + l15;
        const float b = bias[col];
#pragma unroll
        for (int mt = 0; mt < 2; ++mt)
#pragma unroll
            for (int r4 = 0; r4 < 4; ++r4)
                Acc[(mt * 16 + quad * 4 + r4) * ALD + col] = acc[mt][nt][r4] + b;
    }
    __syncthreads();
#pragma unroll
    for (int p = 0; p < 2; ++p) {
        const int q = tid + p * 256;
        const int r = q >> 4;            // 0..31
        const int g = (q & 15) * 8;
        const float4 a = *(const float4*)&Acc[r * ALD + g];
        const float4 b = *(const float4*)&Acc[r * ALD + g + 4];
        f16x8 o = {(_Float16)a.x, (_Float16)a.y, (_Float16)a.z, (_Float16)a.w,
                   (_Float16)b.x, (_Float16)b.y, (_Float16)b.z, (_Float16)b.w};
        *(f16x8*)&Hout[(size_t)(row0 + r) * 128 + g] = o;
    }
}

// ---------------------------------------------------------------------------
// Fused layer 3 + output projection + softmax, 32-row tile.
// Phase A: h2(fp16) + Agg. B1 -> h3 in LDS. B2 (K=512): cols 0..383 from the
// CONTIGUOUS fp16 h0/h1/h2 buffers (2-deep f16x8 pipeline, convert at
// consume), cols 384..511 from LDS. Cst aliases Acc.
// ---------------------------------------------------------------------------
__global__ __launch_bounds__(256, 3) void gin_final(
    const _Float16* __restrict__ h0,           // [GN,128] fp16
    const _Float16* __restrict__ h1,
    const _Float16* __restrict__ h2,
    const float* __restrict__ Agg,             // [GN,128] fp32
    const __bf16* __restrict__ Whi3,           // Wc[2] planes [128,128]
    const __bf16* __restrict__ Wlo3,
    const float* __restrict__ b3,              // [128]
    const __bf16* __restrict__ WhiO,           // W_out planes [64,512]
    const __bf16* __restrict__ WloO,
    const float* __restrict__ bO,              // [64]
    float* __restrict__ out)                   // [GN,64]
{
    constexpr int CLD = 68;

    __shared__ float Smem[32 * ALD];     // 16896 B; Acc and Cst time-share
    float* const Acc = Smem;
    float* const Cst = Smem;

    const int tid  = threadIdx.x;
    const int wave = tid >> 6;
    const int lane = tid & 63;
    const int row0 = blockIdx.x * 32;
    const int quad = lane >> 4;
    const int l15  = lane & 15;
    const int c8   = l15 * 8;

    // ---- Phase A (wave-local): Acc = h2 + Agg ----
#pragma unroll
    for (int p = 0; p < 2; ++p) {
        const int r = wave * 8 + p * 4 + quad;
        const size_t g = (size_t)(row0 + r) * 128 + c8;
        const f16x8 hv = *(const f16x8*)(h2 + g);
        const f32x4 a0 = *(const f32x4*)(Agg + g);
        const f32x4 a1 = *(const f32x4*)(Agg + g + 4);
        f32x4 v0, v1;
#pragma unroll
        for (int e = 0; e < 4; ++e) {
            v0[e] = (float)hv[e]     + a0[e];
            v1[e] = (float)hv[e + 4] + a1[e];
        }
        *(f32x4*)&Acc[r * ALD + c8]     = v0;
        *(f32x4*)&Acc[r * ALD + c8 + 4] = v1;
    }
    __syncthreads();

    // ---- Phase B1: GEMM1 (K=128) -> h3 ----
    const int wn = wave * 32;
    f32x4 acc1[2][2];
    gemm_tile(Acc, Whi3, Wlo3, wn, quad, l15, acc1);
    __syncthreads();

    // h3 + b3 -> Acc (overwrites staged input; all reads done)
#pragma unroll
    for (int nt = 0; nt < 2; ++nt) {
        const int col = wn + nt * 16 + l15;
        const float b = b3[col];
#pragma unroll
        for (int mt = 0; mt < 2; ++mt)
#pragma unroll
            for (int r4 = 0; r4 < 4; ++r4)
                Acc[(mt * 16 + quad * 4 + r4) * ALD + col] = acc1[mt][nt][r4] + b;
    }
    __syncthreads();

    // ---- Phase B2: GEMM2 (K=512), 1m x 2n x 2k waves ----
    const int wk  = wave & 1;
    const int wn2 = (wave >> 1) * 32;
    f32x4 acc2[2][2];
#pragma unroll
    for (int i = 0; i < 2; ++i)
#pragma unroll
        for (int j = 0; j < 2; ++j) acc2[i][j] = (f32x4)(0.0f);

    f16x8 hA[2], hB[2];
    bf16x8 whA[2], wlA[2], whB[2], wlB[2];

    // prologue: ks=0 fragment is always global (kg <= 280 < 384)
    {
        const int kg = wk * 256 + quad * 8;
        const _Float16* hb = (kg < 128) ? h0 : (kg < 256) ? h1 : h2;
        const int kc = kg & 127;
#pragma unroll
        for (int mt = 0; mt < 2; ++mt) {
            const int row = mt * 16 + l15;
            hA[mt] = *(const f16x8*)(hb + (size_t)(row0 + row) * 128 + kc);
        }
#pragma unroll
        for (int nt = 0; nt < 2; ++nt) {
            const int n = wn2 + nt * 16 + l15;
            whA[nt] = *(const bf16x8*)(WhiO + (size_t)n * 512 + kg);
            wlA[nt] = *(const bf16x8*)(WloO + (size_t)n * 512 + kg);
        }
    }

#pragma unroll
    for (int ks = 0; ks < 8; ++ks) {
        const int kgC = wk * 256 + ks * 32 + quad * 8;
        if (ks < 7) {
            const int kgN = kgC + 32;
            if (kgN < 384) {
                const _Float16* hb = (kgN < 128) ? h0 : (kgN < 256) ? h1 : h2;
                const int kc = kgN & 127;
#pragma unroll
                for (int mt = 0; mt < 2; ++mt) {
                    const int row = mt * 16 + l15;
                    hB[mt] = *(const f16x8*)(hb + (size_t)(row0 + row) * 128 + kc);
                }
            }
#pragma unroll
            for (int nt = 0; nt < 2; ++nt) {
                const int n = wn2 + nt * 16 + l15;
                whB[nt] = *(const bf16x8*)(WhiO + (size_t)n * 512 + kgN);
                wlB[nt] = *(const bf16x8*)(WloO + (size_t)n * 512 + kgN);
            }
        }
        bf16x8 ahi[2], alo[2];
#pragma unroll
        for (int mt = 0; mt < 2; ++mt) {
            if (kgC < 384) {
#pragma unroll
                for (int e = 0; e < 8; ++e) {
                    const float v = (float)hA[mt][e];
                    const __bf16 hp = (__bf16)v;
                    ahi[mt][e] = hp;
                    alo[mt][e] = (__bf16)(v - (float)hp);
                }
            } else {
                const int row = mt * 16 + l15;
                const float* ap = &Acc[row * ALD + (kgC - 384)];
                const f32x4 p = *(const f32x4*)ap;
                const f32x4 q = *(const f32x4*)(ap + 4);
#pragma unroll
                for (int e = 0; e < 4; ++e) {
                    const __bf16 hp = (__bf16)p[e];
                    const __bf16 hq = (__bf16)q[e];
                    ahi[mt][e]     = hp;
                    ahi[mt][e + 4] = hq;
                    alo[mt][e]     = (__bf16)(p[e] - (float)hp);
                    alo[mt][e + 4] = (__bf16)(q[e] - (float)hq);
                }
            }
        }
#pragma unroll
        for (int mt = 0; mt < 2; ++mt)
#pragma unroll
            for (int nt = 0; nt < 2; ++nt) {
                acc2[mt][nt] = __builtin_amdgcn_mfma_f32_16x16x32_bf16(
                    ahi[mt], whA[nt], acc2[mt][nt], 0, 0, 0);
                acc2[mt][nt] = __builtin_amdgcn_mfma_f32_16x16x32_bf16(
                    ahi[mt], wlA[nt], acc2[mt][nt], 0, 0, 0);
                acc2[mt][nt] = __builtin_amdgcn_mfma_f32_16x16x32_bf16(
                    alo[mt], whA[nt], acc2[mt][nt], 0, 0, 0);
            }
        if (ks < 7) {
#pragma unroll
            for (int mt = 0; mt < 2; ++mt) hA[mt] = hB[mt];
#pragma unroll
            for (int nt = 0; nt < 2; ++nt) { whA[nt] = whB[nt]; wlA[nt] = wlB[nt]; }
        }
    }

    __syncthreads();   // all B2 reads of Acc done before Cst alias write

    // ---- k-half reduction in Cst ----
    if (wk == 1) {
#pragma unroll
        for (int nt = 0; nt < 2; ++nt)
#pragma unroll
            for (int mt = 0; mt < 2; ++mt)
#pragma unroll
                for (int r4 = 0; r4 < 4; ++r4)
                    Cst[(mt * 16 + quad * 4 + r4) * CLD + wn2 + nt * 16 + l15]
                        = acc2[mt][nt][r4];
    }
    __syncthreads();
    if (wk == 0) {
#pragma unroll
        for (int nt = 0; nt < 2; ++nt) {
            const int col = wn2 + nt * 16 + l15;
            const float b = bO[col];
#pragma unroll
            for (int mt = 0; mt < 2; ++mt)
#pragma unroll
                for (int r4 = 0; r4 < 4; ++r4) {
                    const int idx = (mt * 16 + quad * 4 + r4) * CLD + col;
                    Cst[idx] = Cst[idx] + acc2[mt][nt][r4] + b;
                }
        }
    }
    __syncthreads();

    // ---- Phase C: softmax, 4 waves x 8 rows ----
    for (int i = 0; i < 8; ++i) {
        const int r = wave * 8 + i;
        const float v = Cst[r * CLD + lane];
        float m = v;
#pragma unroll
        for (int off = 32; off > 0; off >>= 1) m = fmaxf(m, __shfl_xor(m, off));
        const float e = __expf(v - m);
        float s = e;
#pragma unroll
        for (int off = 32; off > 0; off >>= 1) s += __shfl_xor(s, off);
        out[(size_t)(row0 + r) * 64 + lane] = e / s;
    }
}

// ---------------------------------------------------------------------------
// CSR construction (unchanged)
// ---------------------------------------------------------------------------
__global__ __launch_bounds__(256) void count_deg(const int* __restrict__ dst,
                                                 int* __restrict__ deg)
{
    const int e = blockIdx.x * 256 + threadIdx.x;
    if (e < GE) atomicAdd(&deg[dst[e]], 1);
}

__global__ __launch_bounds__(256) void scan_pass1(const int* __restrict__ deg,
                                                  int* __restrict__ excl,
                                                  int* __restrict__ blockSums)
{
    __shared__ int s[256];
    const int t = threadIdx.x;
    const int base = blockIdx.x * 1024 + t * 4;

    int4 v = make_int4(0, 0, 0, 0);
    if (base + 3 < GN) {
        v = *(const int4*)(deg + base);
    } else {
        if (base + 0 < GN) v.x = deg[base + 0];
        if (base + 1 < GN) v.y = deg[base + 1];
        if (base + 2 < GN) v.z = deg[base + 2];
        if (base + 3 < GN) v.w = deg[base + 3];
    }
    const int mysum = v.x + v.y + v.z + v.w;
    s[t] = mysum;
    __syncthreads();
    for (int off = 1; off < 256; off <<= 1) {
        const int val = (t >= off) ? s[t - off] : 0;
        __syncthreads();
        s[t] += val;
        __syncthreads();
    }
    int4 o;
    o.x = s[t] - mysum;
    o.y = o.x + v.x;
    o.z = o.y + v.y;
    o.w = o.z + v.z;
    if (base + 3 < GN) {
        *(int4*)(excl + base) = o;
    } else {
        if (base + 0 < GN) excl[base + 0] = o.x;
        if (base + 1 < GN) excl[base + 1] = o.y;
        if (base + 2 < GN) excl[base + 2] = o.z;
        if (base + 3 < GN) excl[base + 3] = o.w;
    }
    if (t == 255) blockSums[blockIdx.x] = s[255];
}

__global__ __launch_bounds__(128) void scan_pass2(const int* __restrict__ blockSums,
                                                  int* __restrict__ blockOffs, int n)
{
    __shared__ int s[128];
    const int t = threadIdx.x;
    const int v = (t < n) ? blockSums[t] : 0;
    s[t] = v;
    __syncthreads();
    for (int off = 1; off < 128; off <<= 1) {
        const int val = (t >= off) ? s[t - off] : 0;
        __syncthreads();
        s[t] += val;
        __syncthreads();
    }
    if (t < n) blockOffs[t] = s[t] - v;
}

__global__ __launch_bounds__(256) void scan_pass3(int* __restrict__ excl,
                                                  const int* __restrict__ blockOffs,
                                                  int* __restrict__ cursor)
{
    const int i = blockIdx.x * 256 + threadIdx.x;
    if (i >= GN) return;
    const int v = excl[i] + blockOffs[i >> 10];
    excl[i]   = v;
    cursor[i] = v;
}

__global__ __launch_bounds__(256) void fill_csr(const int* __restrict__ src,
                                                const int* __restrict__ dst,
                                                int* __restrict__ cursor,
                                                int* __restrict__ csr)
{
    const int e = blockIdx.x * 256 + threadIdx.x;
    if (e >= GE) return;
    const int pos = atomicAdd(&cursor[dst[e]], 1);
    csr[pos] = src[e];
}

extern "C" void kernel_launch(void* const* d_in, const int* in_sizes, int n_in,
                              void* d_out, int out_size, void* d_ws, size_t ws_size,
                              hipStream_t stream)
{
    const float* x       = (const float*)d_in[0];
    const int*   src     = (const int*)d_in[1];
    const int*   dst     = ((const int*)d_in[1]) + GE;
    const float* W_in    = (const float*)d_in[2];
    const float* b_in    = (const float*)d_in[3];
    const float* W_convs = (const float*)d_in[4];
    const float* b_convs = (const float*)d_in[5];
    const float* W_out   = (const float*)d_in[6];
    const float* b_out   = (const float*)d_in[7];
    float*       out     = (float*)d_out;

    // d_ws layout (~131 MB; working set now fits the 256 MB LLC):
    //   h0|h1|h2 fp16 [GN,128] each | Agg fp32 [GN,128] | CSR scratch |
    //   hi/lo weight planes.
    _Float16* h0 = (_Float16*)d_ws;
    _Float16* h1 = h0 + (size_t)GN * 128;
    _Float16* h2 = h1 + (size_t)GN * 128;
    float*    Agg = (float*)(h2 + (size_t)GN * 128);
    int*      deg       = (int*)(Agg + (size_t)GN * 128);
    int*      row_start = deg + GN;
    int*      cursor    = row_start + GN;
    int*      blockSums = cursor + GN;
    int*      blockOffs = blockSums + 128;
    int*      csr       = blockOffs + 128;
    __bf16*   Whi       = (__bf16*)(csr + GE);
    __bf16*   Wlo       = Whi + 98304;

    const dim3 blk(256);
    const dim3 gblk(256);
    const int edge_blocks   = (GE + 255) / 256;
    const int node_blocks   = (GN + 255) / 256;
    const int layer_blocks  = GN / 32;           // 3125 (exact)
    const int gather_blocks = (GN + 3) / 4;

    // --- CSR build ---
    hipMemsetAsync(deg, 0, GN * sizeof(int), stream);
    count_deg<<<edge_blocks, blk, 0, stream>>>(dst, deg);
    scan_pass1<<<SCAN_NBLK, blk, 0, stream>>>(deg, row_start, blockSums);
    scan_pass2<<<1, 128, 0, stream>>>(blockSums, blockOffs, SCAN_NBLK);
    scan_pass3<<<node_blocks, blk, 0, stream>>>(row_start, blockOffs, cursor);
    fill_csr<<<edge_blocks, blk, 0, stream>>>(src, dst, cursor, csr);

    // --- weight pre-conversion ---
    convert_w<<<(98304 + 255) / 256, blk, 0, stream>>>(W_in, W_convs, W_out, Whi, Wlo);

    // --- input projection -> h0 ---
    gin_layer<false><<<layer_blocks, gblk, 0, stream>>>(
        x, nullptr, nullptr, Whi, Wlo, b_in, h0);

    // --- layer 1: gather(h0) -> Agg; (h0+Agg)@W1 -> h1 ---
    gather_rows<<<gather_blocks, gblk, 0, stream>>>(
        (const uint*)h0, row_start, deg, csr, Agg);
    gin_layer<true><<<layer_blocks, gblk, 0, stream>>>(
        nullptr, h0, Agg, Whi + 16384, Wlo + 16384, b_convs, h1);

    // --- layer 2: gather(h1) -> Agg; (h1+Agg)@W2 -> h2 ---
    gather_rows<<<gather_blocks, gblk, 0, stream>>>(
        (const uint*)h1, row_start, deg, csr, Agg);
    gin_layer<true><<<layer_blocks, gblk, 0, stream>>>(
        nullptr, h1, Agg, Whi + 32768, Wlo + 32768, b_convs + 128, h2);

    // --- layer 3 + output projection + softmax ---
    gather_rows<<<gather_blocks, gblk, 0, stream>>>(
        (const uint*)h2, row_start, deg, csr, Agg);
    gin_final<<<layer_blocks, gblk, 0, stream>>>(
        h0, h1, h2, Agg, Whi + 49152, Wlo + 49152, b_convs + 256,
        Whi + 65536, Wlo + 65536, b_out, out);
}